// Round 3
// baseline (686.657 us; speedup 1.0000x reference)
//
#include <hip/hip_runtime.h>
#include <hip/hip_bf16.h>
#include <cstddef>

#define T_TOK 512
#define D_DIM 1024
#define E_EXP 64
#define INTER 512
#define TOPK 4

// ---------------- Router: 1 wave per token ----------------
__global__ __launch_bounds__(64) void router_kernel(
    const float* __restrict__ x, const float* __restrict__ gate_w,
    int* __restrict__ cnt, int* __restrict__ list, float* __restrict__ pairw) {
  const int t = blockIdx.x;
  const int e = threadIdx.x;  // 0..63, one expert per lane
  const float4* xr = (const float4*)(x + (size_t)t * D_DIM);
  const float4* gr = (const float4*)(gate_w + (size_t)e * D_DIM);
  float acc = 0.f;
#pragma unroll 8
  for (int i = 0; i < D_DIM / 4; i++) {
    float4 a = xr[i], b = gr[i];
    acc += a.x * b.x + a.y * b.y + a.z * b.z + a.w * b.w;
  }
  // softmax over 64 lanes
  float m = acc;
  for (int off = 32; off; off >>= 1) m = fmaxf(m, __shfl_xor(m, off, 64));
  float p = __expf(acc - m);
  float s = p;
  for (int off = 32; off; off >>= 1) s += __shfl_xor(s, off, 64);
  float prob = p / s;

  // top-4 via 4x butterfly argmax
  float val = prob;
  int ids[TOPK];
  float ws[TOPK];
  float wsum = 0.f;
#pragma unroll
  for (int k = 0; k < TOPK; k++) {
    float v = val;
    int idx = e;
    for (int off = 32; off; off >>= 1) {
      float ov = __shfl_xor(v, off, 64);
      int oi = __shfl_xor(idx, off, 64);
      if (ov > v || (ov == v && oi < idx)) { v = ov; idx = oi; }
    }
    ids[k] = idx;
    ws[k] = v;
    wsum += v;
    if (e == idx) val = -1.f;
  }
  if (e < TOPK) {
    const int k = e;
    const int ex = ids[k];
    const float w = ws[k] / wsum;
    const int p_id = t * TOPK + k;
    pairw[p_id] = w;
    const int pos = atomicAdd(&cnt[ex], 1);
    list[ex * T_TOK + pos] = p_id;
  }
}

// ---------------- Stage 1: gate+up GEMM + SiLU ----------------
// grid (E=64, INTER/BF1=16) = 1024 blocks, 128 threads.
// Block tile BF1=32 f x BT1=64 slots, BK1=64. One token-tile per block
// (P(n>64) ~ 0), uniform 16-iteration K-loop, register-prefetch pipeline.
// Thread grid 8(f) x 16(t); thread tile 4f x 4t.
// LDS row stride 68 floats: measured 0 bank conflicts in R2 with this pattern.
#define BF1 32
#define BT1 64
#define BK1 64
#define LD1 (BK1 + 4)
__global__ __launch_bounds__(128) void stage1_kernel(
    const float* __restrict__ x, const float* __restrict__ w_gate,
    const float* __restrict__ w_up, const int* __restrict__ cnt,
    const int* __restrict__ list, const float* __restrict__ pairw,
    float* __restrict__ h) {
  const int e = blockIdx.x;
  const int fbase = blockIdx.y * BF1;
  const int n = cnt[e];
  if (n == 0) return;
  __shared__ float wg[BF1][LD1];
  __shared__ float wu[BF1][LD1];
  __shared__ float xt[BT1][LD1];
  const int tid = threadIdx.x;
  const int f0 = tid & 7;
  const int t0 = tid >> 3;  // 0..15
  const float* Wg = w_gate + ((size_t)e * INTER + fbase) * D_DIM;
  const float* Wu = w_up + ((size_t)e * INTER + fbase) * D_DIM;
  const int* mylist = list + e * T_TOK;
  const int srow = tid >> 4;         // 0..7
  const int sc4 = (tid & 15) << 2;   // 0..60

  for (int tb = 0; tb < n; tb += BT1) {
    // gathered x row base pointers for staging
    const float* xrow[8];
#pragma unroll
    for (int r = 0; r < 8; r++) {
      const int slot = tb + srow + 8 * r;
      const int pid = mylist[slot < n ? slot : 0];
      xrow[r] = x + (size_t)(pid >> 2) * D_DIM + sc4;
    }
    float accg[4][4], accu[4][4];
#pragma unroll
    for (int i = 0; i < 4; i++)
#pragma unroll
      for (int j = 0; j < 4; j++) { accg[i][j] = 0.f; accu[i][j] = 0.f; }

    float4 pg[4], pu[4], px[8];
    // prefetch K-tile 0
#pragma unroll
    for (int r = 0; r < 4; r++) {
      pg[r] = *(const float4*)(Wg + (size_t)(srow + 8 * r) * D_DIM + sc4);
      pu[r] = *(const float4*)(Wu + (size_t)(srow + 8 * r) * D_DIM + sc4);
    }
#pragma unroll
    for (int r = 0; r < 8; r++) px[r] = *(const float4*)xrow[r];

    for (int kb = 0; kb < D_DIM; kb += BK1) {
      if (kb) __syncthreads();  // prior readers done before overwriting LDS
#pragma unroll
      for (int r = 0; r < 4; r++) {
        *(float4*)&wg[srow + 8 * r][sc4] = pg[r];
        *(float4*)&wu[srow + 8 * r][sc4] = pu[r];
      }
#pragma unroll
      for (int r = 0; r < 8; r++) *(float4*)&xt[srow + 8 * r][sc4] = px[r];
      __syncthreads();
      // issue next tile's global loads BEFORE compute (overlap latency)
      if (kb + BK1 < D_DIM) {
        const int k2 = kb + BK1;
#pragma unroll
        for (int r = 0; r < 4; r++) {
          pg[r] = *(const float4*)(Wg + (size_t)(srow + 8 * r) * D_DIM + k2 + sc4);
          pu[r] = *(const float4*)(Wu + (size_t)(srow + 8 * r) * D_DIM + k2 + sc4);
        }
#pragma unroll
        for (int r = 0; r < 8; r++) px[r] = *(const float4*)(xrow[r] + k2);
      }
#pragma unroll
      for (int k4 = 0; k4 < BK1; k4 += 4) {
        float4 wgv[4], wuv[4], xv[4];
#pragma unroll
        for (int i = 0; i < 4; i++) {
          wgv[i] = *(const float4*)&wg[f0 + 8 * i][k4];
          wuv[i] = *(const float4*)&wu[f0 + 8 * i][k4];
        }
#pragma unroll
        for (int j = 0; j < 4; j++) xv[j] = *(const float4*)&xt[t0 + 16 * j][k4];
#pragma unroll
        for (int kk = 0; kk < 4; kk++) {
#pragma unroll
          for (int i = 0; i < 4; i++) {
            const float a = ((const float*)&wgv[i])[kk];
            const float b = ((const float*)&wuv[i])[kk];
#pragma unroll
            for (int j = 0; j < 4; j++) {
              const float xx = ((const float*)&xv[j])[kk];
              accg[i][j] += a * xx;
              accu[i][j] += b * xx;
            }
          }
        }
      }
    }
    // epilogue: h[p][f] = w_p * silu(g) * u
#pragma unroll
    for (int j = 0; j < 4; j++) {
      const int slot = tb + t0 + 16 * j;
      if (slot < n) {
        const int pid = mylist[slot];
        const float wp = pairw[pid];
        float* hp = h + (size_t)pid * INTER + fbase;
#pragma unroll
        for (int i = 0; i < 4; i++) {
          const float g = accg[i][j];
          const float u = accu[i][j];
          const float sg = g / (1.f + __expf(-g));
          hp[f0 + 8 * i] = wp * sg * u;
        }
      }
    }
    if (tb + BT1 < n) __syncthreads();
  }
}

// ---------------- Stage 2: down GEMM, atomic accumulate ----------------
// grid (E=64, D/BF2=16) = 1024 blocks, 128 threads.
// Block tile BF2=64 d x BT2=64 slots, BK2=64; 8 K-iters, register prefetch.
// Thread grid 16(d) x 8(t); thread tile 4d x 8t.
#define BF2 64
#define BT2 64
#define BK2 64
#define LD2 (BK2 + 4)
__global__ __launch_bounds__(128) void stage2_kernel(
    const float* __restrict__ w_down, const int* __restrict__ cnt,
    const int* __restrict__ list, const float* __restrict__ h,
    float* __restrict__ out) {
  const int e = blockIdx.x;
  const int dbase = blockIdx.y * BF2;
  const int n = cnt[e];
  if (n == 0) return;
  __shared__ float wd[BF2][LD2];
  __shared__ float ht[BT2][LD2];
  const int tid = threadIdx.x;
  const int d0 = tid & 15;
  const int t0 = tid >> 4;  // 0..7
  const float* Wd = w_down + ((size_t)e * D_DIM + dbase) * INTER;
  const int* mylist = list + e * T_TOK;
  const int srow = tid >> 4;        // 0..7
  const int sc4 = (tid & 15) << 2;  // 0..60

  for (int tb = 0; tb < n; tb += BT2) {
    const float* hrow[8];
#pragma unroll
    for (int r = 0; r < 8; r++) {
      const int slot = tb + srow + 8 * r;
      const int pid = mylist[slot < n ? slot : 0];
      hrow[r] = h + (size_t)pid * INTER + sc4;
    }
    float acc[4][8];
#pragma unroll
    for (int i = 0; i < 4; i++)
#pragma unroll
      for (int j = 0; j < 8; j++) acc[i][j] = 0.f;

    float4 pw[8], ph[8];
#pragma unroll
    for (int r = 0; r < 8; r++) {
      pw[r] = *(const float4*)(Wd + (size_t)(srow + 8 * r) * INTER + sc4);
      ph[r] = *(const float4*)hrow[r];
    }

    for (int kb = 0; kb < INTER; kb += BK2) {
      if (kb) __syncthreads();
#pragma unroll
      for (int r = 0; r < 8; r++) {
        *(float4*)&wd[srow + 8 * r][sc4] = pw[r];
        *(float4*)&ht[srow + 8 * r][sc4] = ph[r];
      }
      __syncthreads();
      if (kb + BK2 < INTER) {
        const int k2 = kb + BK2;
#pragma unroll
        for (int r = 0; r < 8; r++) {
          pw[r] = *(const float4*)(Wd + (size_t)(srow + 8 * r) * INTER + k2 + sc4);
          ph[r] = *(const float4*)(hrow[r] + k2);
        }
      }
#pragma unroll
      for (int k4 = 0; k4 < BK2; k4 += 4) {
        float4 wv[4], hv[8];
#pragma unroll
        for (int i = 0; i < 4; i++) wv[i] = *(const float4*)&wd[d0 + 16 * i][k4];
#pragma unroll
        for (int j = 0; j < 8; j++) hv[j] = *(const float4*)&ht[t0 + 8 * j][k4];
#pragma unroll
        for (int kk = 0; kk < 4; kk++) {
#pragma unroll
          for (int i = 0; i < 4; i++) {
            const float a = ((const float*)&wv[i])[kk];
#pragma unroll
            for (int j = 0; j < 8; j++) {
              acc[i][j] += a * ((const float*)&hv[j])[kk];
            }
          }
        }
      }
    }
    // epilogue: atomic accumulate (combine weight folded into h)
#pragma unroll
    for (int j = 0; j < 8; j++) {
      const int slot = tb + t0 + 8 * j;
      if (slot < n) {
        const int tok = mylist[slot] >> 2;
        float* op = out + (size_t)tok * D_DIM + dbase;
#pragma unroll
        for (int i = 0; i < 4; i++) {
          atomicAdd(&op[d0 + 16 * i], acc[i][j]);
        }
      }
    }
    if (tb + BT2 < n) __syncthreads();
  }
}

extern "C" void kernel_launch(void* const* d_in, const int* in_sizes, int n_in,
                              void* d_out, int out_size, void* d_ws, size_t ws_size,
                              hipStream_t stream) {
  const float* x = (const float*)d_in[0];       // [T, D]
  const float* gate_w = (const float*)d_in[1];  // [E, D]
  const float* w_gate = (const float*)d_in[2];  // [E, INTER, D]
  const float* w_up = (const float*)d_in[3];    // [E, INTER, D]
  const float* w_down = (const float*)d_in[4];  // [E, D, INTER]
  float* out = (float*)d_out;                   // [T, D]

  char* ws = (char*)d_ws;
  int* cnt = (int*)ws;                                     // E ints
  int* list = (int*)(ws + 256);                            // E*T ints
  float* pairw = (float*)(ws + 256 + E_EXP * T_TOK * 4);   // T*K floats
  float* h = (float*)(ws + 256 + E_EXP * T_TOK * 4 + T_TOK * TOPK * 4);  // [T*K, INTER]

  hipMemsetAsync(cnt, 0, E_EXP * sizeof(int), stream);
  hipMemsetAsync(out, 0, (size_t)T_TOK * D_DIM * sizeof(float), stream);

  router_kernel<<<T_TOK, 64, 0, stream>>>(x, gate_w, cnt, list, pairw);
  stage1_kernel<<<dim3(E_EXP, INTER / BF1), 128, 0, stream>>>(
      x, w_gate, w_up, cnt, list, pairw, h);
  stage2_kernel<<<dim3(E_EXP, D_DIM / BF2), 128, 0, stream>>>(
      w_down, cnt, list, h, out);
}

// Round 4
// 513.739 us; speedup vs baseline: 1.3366x; 1.3366x over previous
//
#include <hip/hip_runtime.h>
#include <hip/hip_bf16.h>
#include <cstddef>

#define T_TOK 512
#define D_DIM 1024
#define E_EXP 64
#define INTER 512
#define TOPK 4

// async global->LDS, 16B per lane; LDS dst is wave-uniform base + lane*16.
__device__ __forceinline__ void async16(float4* ldsdst, const float* g) {
  __builtin_amdgcn_global_load_lds(
      (const __attribute__((address_space(1))) void*)g,
      (__attribute__((address_space(3))) void*)ldsdst, 16, 0, 0);
}

// ---------------- Router: 1 wave per token ----------------
__global__ __launch_bounds__(64) void router_kernel(
    const float* __restrict__ x, const float* __restrict__ gate_w,
    int* __restrict__ cnt, int* __restrict__ list, float* __restrict__ pairw) {
  const int t = blockIdx.x;
  const int e = threadIdx.x;
  const float4* xr = (const float4*)(x + (size_t)t * D_DIM);
  const float4* gr = (const float4*)(gate_w + (size_t)e * D_DIM);
  float acc = 0.f;
#pragma unroll 8
  for (int i = 0; i < D_DIM / 4; i++) {
    float4 a = xr[i], b = gr[i];
    acc += a.x * b.x + a.y * b.y + a.z * b.z + a.w * b.w;
  }
  float m = acc;
  for (int off = 32; off; off >>= 1) m = fmaxf(m, __shfl_xor(m, off, 64));
  float p = __expf(acc - m);
  float s = p;
  for (int off = 32; off; off >>= 1) s += __shfl_xor(s, off, 64);
  float prob = p / s;

  float val = prob;
  int ids[TOPK];
  float ws[TOPK];
  float wsum = 0.f;
#pragma unroll
  for (int k = 0; k < TOPK; k++) {
    float v = val;
    int idx = e;
    for (int off = 32; off; off >>= 1) {
      float ov = __shfl_xor(v, off, 64);
      int oi = __shfl_xor(idx, off, 64);
      if (ov > v || (ov == v && oi < idx)) { v = ov; idx = oi; }
    }
    ids[k] = idx;
    ws[k] = v;
    wsum += v;
    if (e == idx) val = -1.f;
  }
  if (e < TOPK) {
    const int k = e;
    const int ex = ids[k];
    const float w = ws[k] / wsum;
    const int p_id = t * TOPK + k;
    pairw[p_id] = w;
    const int pos = atomicAdd(&cnt[ex], 1);
    list[ex * T_TOK + pos] = p_id;
  }
}

// ---------------- Stage 1: gate+up GEMM + SiLU ----------------
// grid (E=64, INTER/32=16), 256 threads (4 waves).
// Block tile 32f x 64t, BK=64. Double-buffered LDS fed by global_load_lds.
// LDS f4 layout per buffer: wg [0,512), wu [512,1024), xt [1024,2048).
// XOR swizzle: data (row,col_f4) stored at phys row*16 + (col ^ (row&7)).
// Staging: wave0 -> wg, wave1 -> wu, wave2/3 -> xt (gathered token rows).
#define BF1 32
#define BT1 64
#define BK1 64
__global__ __launch_bounds__(256) void stage1_kernel(
    const float* __restrict__ x, const float* __restrict__ w_gate,
    const float* __restrict__ w_up, const int* __restrict__ cnt,
    const int* __restrict__ list, const float* __restrict__ pairw,
    float* __restrict__ h) {
  const int e = blockIdx.x;
  const int fbase = blockIdx.y * BF1;
  const int n = cnt[e];
  if (n == 0) return;
  __shared__ float4 lds[2][2048];  // 64 KB
  const int tid = threadIdx.x;
  const int w = tid >> 6;
  const int lane = tid & 63;
  const int f0 = tid & 15;   // 16 f-threads, tile 2f (f0+16i)
  const int t0 = tid >> 4;   // 16 t-threads, tile 4t (t0+16j)
  const float* Wg = w_gate + ((size_t)e * INTER + fbase) * D_DIM;
  const float* Wu = w_up + ((size_t)e * INTER + fbase) * D_DIM;
  const int* mylist = list + e * T_TOK;

  // weight staging offsets (waves 0/1): chunk r covers rows 4r..4r+3
  int woff[8];
#pragma unroll
  for (int r = 0; r < 8; r++) {
    const int idx = r * 64 + lane;
    const int row = idx >> 4;
    const int col = (idx & 15) ^ (row & 7);
    woff[r] = row * D_DIM + 4 * col;
  }

  for (int tb = 0; tb < n; tb += BT1) {
    // gathered x row pointers (waves 2/3)
    const float* xp[8];
    if (w >= 2) {
#pragma unroll
      for (int r = 0; r < 8; r++) {
        const int c = (w - 2) * 8 + r;
        const int idx = c * 64 + lane;
        const int row = idx >> 4;
        const int col = (idx & 15) ^ (row & 7);
        const int slot = tb + row;
        const int pid = mylist[slot < n ? slot : 0];
        xp[r] = x + (size_t)(pid >> 2) * D_DIM + 4 * col;
      }
    }
    auto stage = [&](int buf, int kb) {
      float4* B = &lds[buf][0];
      if (w == 0) {
#pragma unroll
        for (int r = 0; r < 8; r++) async16(B + r * 64, Wg + woff[r] + kb);
      } else if (w == 1) {
#pragma unroll
        for (int r = 0; r < 8; r++) async16(B + 512 + r * 64, Wu + woff[r] + kb);
      } else {
        const int c0 = (w - 2) * 8;
#pragma unroll
        for (int r = 0; r < 8; r++)
          async16(B + 1024 + (c0 + r) * 64, xp[r] + kb);
      }
    };

    float accg[2][4], accu[2][4];
#pragma unroll
    for (int i = 0; i < 2; i++)
#pragma unroll
      for (int j = 0; j < 4; j++) { accg[i][j] = 0.f; accu[i][j] = 0.f; }

    stage(0, 0);  // prologue
    for (int ki = 0; ki < D_DIM / BK1; ki++) {
      __syncthreads();  // drains DMA for current buffer; readers of prev done
      if (ki + 1 < D_DIM / BK1) stage((ki + 1) & 1, (ki + 1) * BK1);
      const float4* wgb = &lds[ki & 1][0];
      const float4* wub = wgb + 512;
      const float4* xtb = wgb + 1024;
#pragma unroll
      for (int k4 = 0; k4 < 16; k4++) {
        float4 wgv[2], wuv[2], xv[4];
#pragma unroll
        for (int i = 0; i < 2; i++) {
          const int off = (f0 + 16 * i) * 16 + (k4 ^ (f0 & 7));
          wgv[i] = wgb[off];
          wuv[i] = wub[off];
        }
#pragma unroll
        for (int j = 0; j < 4; j++)
          xv[j] = xtb[(t0 + 16 * j) * 16 + (k4 ^ (t0 & 7))];
#pragma unroll
        for (int kk = 0; kk < 4; kk++) {
#pragma unroll
          for (int i = 0; i < 2; i++) {
            const float a = ((const float*)&wgv[i])[kk];
            const float b = ((const float*)&wuv[i])[kk];
#pragma unroll
            for (int j = 0; j < 4; j++) {
              const float xx = ((const float*)&xv[j])[kk];
              accg[i][j] += a * xx;
              accu[i][j] += b * xx;
            }
          }
        }
      }
    }
    // epilogue: h[p][f] = w_p * silu(g) * u
#pragma unroll
    for (int j = 0; j < 4; j++) {
      const int slot = tb + t0 + 16 * j;
      if (slot < n) {
        const int pid = mylist[slot];
        const float wp = pairw[pid];
        float* hp = h + (size_t)pid * INTER + fbase;
#pragma unroll
        for (int i = 0; i < 2; i++) {
          const float g = accg[i][j];
          const float u = accu[i][j];
          hp[f0 + 16 * i] = wp * (g / (1.f + __expf(-g))) * u;
        }
      }
    }
  }
}

// ---------------- Stage 2: down GEMM, atomic accumulate ----------------
// grid (E=64, D/64=16), 256 threads. Block tile 64d x 64t, BK=64.
// LDS f4 layout per buffer: wd [0,1024), ht [1024,2048).
// Staging: wave0/1 -> wd, wave2/3 -> ht (gathered h rows).
#define BF2 64
#define BT2 64
#define BK2 64
__global__ __launch_bounds__(256) void stage2_kernel(
    const float* __restrict__ w_down, const int* __restrict__ cnt,
    const int* __restrict__ list, const float* __restrict__ h,
    float* __restrict__ out) {
  const int e = blockIdx.x;
  const int dbase = blockIdx.y * BF2;
  const int n = cnt[e];
  if (n == 0) return;
  __shared__ float4 lds[2][2048];  // 64 KB
  const int tid = threadIdx.x;
  const int w = tid >> 6;
  const int lane = tid & 63;
  const int d0 = tid & 15;  // tile 4d (d0+16i)
  const int t0 = tid >> 4;  // tile 4t (t0+16j)
  const float* Wd = w_down + ((size_t)e * D_DIM + dbase) * INTER;
  const int* mylist = list + e * T_TOK;

  int woff[8];
  if (w < 2) {
#pragma unroll
    for (int r = 0; r < 8; r++) {
      const int c = w * 8 + r;
      const int idx = c * 64 + lane;
      const int row = idx >> 4;
      const int col = (idx & 15) ^ (row & 7);
      woff[r] = row * INTER + 4 * col;
    }
  }

  for (int tb = 0; tb < n; tb += BT2) {
    const float* hp8[8];
    if (w >= 2) {
#pragma unroll
      for (int r = 0; r < 8; r++) {
        const int c = (w - 2) * 8 + r;
        const int idx = c * 64 + lane;
        const int row = idx >> 4;
        const int col = (idx & 15) ^ (row & 7);
        const int slot = tb + row;
        const int pid = mylist[slot < n ? slot : 0];
        hp8[r] = h + (size_t)pid * INTER + 4 * col;
      }
    }
    auto stage = [&](int buf, int kb) {
      float4* B = &lds[buf][0];
      if (w < 2) {
        const int c0 = w * 8;
#pragma unroll
        for (int r = 0; r < 8; r++)
          async16(B + (c0 + r) * 64, Wd + woff[r] + kb);
      } else {
        const int c0 = (w - 2) * 8;
#pragma unroll
        for (int r = 0; r < 8; r++)
          async16(B + 1024 + (c0 + r) * 64, hp8[r] + kb);
      }
    };

    float acc[4][4];
#pragma unroll
    for (int i = 0; i < 4; i++)
#pragma unroll
      for (int j = 0; j < 4; j++) acc[i][j] = 0.f;

    stage(0, 0);
    for (int ki = 0; ki < INTER / BK2; ki++) {
      __syncthreads();
      if (ki + 1 < INTER / BK2) stage((ki + 1) & 1, (ki + 1) * BK2);
      const float4* wdb = &lds[ki & 1][0];
      const float4* htb = wdb + 1024;
#pragma unroll
      for (int k4 = 0; k4 < 16; k4++) {
        float4 wv[4], hv[4];
#pragma unroll
        for (int i = 0; i < 4; i++)
          wv[i] = wdb[(d0 + 16 * i) * 16 + (k4 ^ (d0 & 7))];
#pragma unroll
        for (int j = 0; j < 4; j++)
          hv[j] = htb[(t0 + 16 * j) * 16 + (k4 ^ (t0 & 7))];
#pragma unroll
        for (int kk = 0; kk < 4; kk++) {
#pragma unroll
          for (int i = 0; i < 4; i++) {
            const float a = ((const float*)&wv[i])[kk];
#pragma unroll
            for (int j = 0; j < 4; j++)
              acc[i][j] += a * ((const float*)&hv[j])[kk];
          }
        }
      }
    }
    // epilogue: atomic accumulate (combine weight folded into h)
#pragma unroll
    for (int j = 0; j < 4; j++) {
      const int slot = tb + t0 + 16 * j;
      if (slot < n) {
        const int tok = mylist[slot] >> 2;
        float* op = out + (size_t)tok * D_DIM + dbase;
#pragma unroll
        for (int i = 0; i < 4; i++)
          atomicAdd(&op[d0 + 16 * i], acc[i][j]);
      }
    }
  }
}

extern "C" void kernel_launch(void* const* d_in, const int* in_sizes, int n_in,
                              void* d_out, int out_size, void* d_ws, size_t ws_size,
                              hipStream_t stream) {
  const float* x = (const float*)d_in[0];
  const float* gate_w = (const float*)d_in[1];
  const float* w_gate = (const float*)d_in[2];
  const float* w_up = (const float*)d_in[3];
  const float* w_down = (const float*)d_in[4];
  float* out = (float*)d_out;

  char* ws = (char*)d_ws;
  int* cnt = (int*)ws;
  int* list = (int*)(ws + 256);
  float* pairw = (float*)(ws + 256 + E_EXP * T_TOK * 4);
  float* h = (float*)(ws + 256 + E_EXP * T_TOK * 4 + T_TOK * TOPK * 4);

  hipMemsetAsync(cnt, 0, E_EXP * sizeof(int), stream);
  hipMemsetAsync(out, 0, (size_t)T_TOK * D_DIM * sizeof(float), stream);

  router_kernel<<<T_TOK, 64, 0, stream>>>(x, gate_w, cnt, list, pairw);
  stage1_kernel<<<dim3(E_EXP, INTER / BF1), 256, 0, stream>>>(
      x, w_gate, w_up, cnt, list, pairw, h);
  stage2_kernel<<<dim3(E_EXP, D_DIM / BF2), 256, 0, stream>>>(
      w_down, cnt, list, h, out);
}